// Round 2
// baseline (159.714 us; speedup 1.0000x reference)
//
#include <hip/hip_runtime.h>

// QuantizationLayer: num = rint(x * 2^B - 0.5) (round-half-even == jnp.round);
// num &= 255; emit B bits MSB-first as floats.
//
// B=4: element j's 4 bits are exactly out4[j] (one float4). Thread handles 4
// elements strided by blockDim so EVERY instruction stays coalesced:
//   load:  lanes read contiguous 4 B  (256 B/wave-instr)
//   store: lanes write contiguous 16 B (1 KiB/wave-instr)
// Nontemporal hints on both streams: output is write-once (134 MB >> 32 MB L2),
// input is read-once — keep both out of L2 to avoid writeback churn.

typedef float f32x4 __attribute__((ext_vector_type(4)));

__global__ __launch_bounds__(256) void quant_bits_b4(
        const float* __restrict__ x, f32x4* __restrict__ out4, int n) {
    int base = blockIdx.x * (256 * 4) + threadIdx.x;
#pragma unroll
    for (int k = 0; k < 4; ++k) {
        int e = base + k * 256;
        if (e < n) {
            float v = __builtin_nontemporal_load(x + e);
            // rintf -> v_rndne_f32 (round half to even), matches jnp.round
            int num = (int)rintf(v * 16.0f - 0.5f) & 255;
            f32x4 o;
            o.x = (float)((num >> 3) & 1);
            o.y = (float)((num >> 2) & 1);
            o.z = (float)((num >> 1) & 1);
            o.w = (float)( num       & 1);
            __builtin_nontemporal_store(o, out4 + e);
        }
    }
}

__global__ void quant_bits_generic(const float* __restrict__ x,
                                   float* __restrict__ out, int n,
                                   int B, float step) {
    int i = blockIdx.x * blockDim.x + threadIdx.x;
    if (i >= n) return;
    float v = x[i];
    int num = (int)rintf(v * step - 0.5f) & 255;
    float* o = out + (size_t)i * (size_t)B;
    for (int j = 0; j < B; ++j) {
        o[j] = (float)((num >> (B - 1 - j)) & 1);
    }
}

extern "C" void kernel_launch(void* const* d_in, const int* in_sizes, int n_in,
                              void* d_out, int out_size, void* d_ws, size_t ws_size,
                              hipStream_t stream) {
    const float* x = (const float*)d_in[0];
    int n = in_sizes[0];                 // 4096*2048 = 8388608
    int B = out_size / n;                // recover B host-side (no memcpy)

    if (B == 4) {
        int grid = (n + 1023) / 1024;    // 4 elems/thread, 256 threads/block
        quant_bits_b4<<<grid, 256, 0, stream>>>(x, (f32x4*)d_out, n);
    } else {
        int grid = (n + 255) / 256;
        float step = (float)(1u << B);
        quant_bits_generic<<<grid, 256, 0, stream>>>(x, (float*)d_out, n, B, step);
    }
}

// Round 3
// 159.681 us; speedup vs baseline: 1.0002x; 1.0002x over previous
//
#include <hip/hip_runtime.h>

// QuantizationLayer: num = rint(x * 2^B - 0.5) (round-half-even == jnp.round);
// num &= 255; emit B bits MSB-first as floats.
//
// B=4 fast path: element e's 4 bits are exactly out4[e] (one float4).
// MLP-maximized schedule: each thread issues 8 coalesced dword loads
// (8 outstanding vmcnt) before any dependent compute/store, then 8 coalesced
// nontemporal dwordx4 stores. 512 threads/block, 4096 elems/block, exact grid
// (n = 8M divides evenly) -> zero divergence, 2048 blocks = 8/CU.

typedef float f32x4 __attribute__((ext_vector_type(4)));

__global__ __launch_bounds__(512) void quant_bits_b4_exact(
        const float* __restrict__ x, f32x4* __restrict__ out4) {
    int base = blockIdx.x * (512 * 8) + threadIdx.x;
    float v[8];
#pragma unroll
    for (int k = 0; k < 8; ++k)
        v[k] = __builtin_nontemporal_load(x + base + k * 512);  // all loads in flight
#pragma unroll
    for (int k = 0; k < 8; ++k) {
        int num = (int)rintf(v[k] * 16.0f - 0.5f) & 255;  // v_rndne, RTE == jnp.round
        f32x4 o;
        o.x = (float)((num >> 3) & 1);
        o.y = (float)((num >> 2) & 1);
        o.z = (float)((num >> 1) & 1);
        o.w = (float)( num       & 1);
        __builtin_nontemporal_store(o, out4 + base + k * 512);
    }
}

// Guarded B=4 path for shapes not divisible by 4096.
__global__ __launch_bounds__(256) void quant_bits_b4(
        const float* __restrict__ x, f32x4* __restrict__ out4, int n) {
    int i = blockIdx.x * blockDim.x + threadIdx.x;
    if (i >= n) return;
    int num = (int)rintf(x[i] * 16.0f - 0.5f) & 255;
    f32x4 o;
    o.x = (float)((num >> 3) & 1);
    o.y = (float)((num >> 2) & 1);
    o.z = (float)((num >> 1) & 1);
    o.w = (float)( num       & 1);
    __builtin_nontemporal_store(o, out4 + i);
}

__global__ void quant_bits_generic(const float* __restrict__ x,
                                   float* __restrict__ out, int n,
                                   int B, float step) {
    int i = blockIdx.x * blockDim.x + threadIdx.x;
    if (i >= n) return;
    int num = (int)rintf(x[i] * step - 0.5f) & 255;
    float* o = out + (size_t)i * (size_t)B;
    for (int j = 0; j < B; ++j)
        o[j] = (float)((num >> (B - 1 - j)) & 1);
}

extern "C" void kernel_launch(void* const* d_in, const int* in_sizes, int n_in,
                              void* d_out, int out_size, void* d_ws, size_t ws_size,
                              hipStream_t stream) {
    const float* x = (const float*)d_in[0];
    int n = in_sizes[0];                 // 4096*2048 = 8388608
    int B = out_size / n;                // recover B host-side (no memcpy)

    if (B == 4) {
        if (n % 4096 == 0) {
            quant_bits_b4_exact<<<n / 4096, 512, 0, stream>>>(x, (f32x4*)d_out);
        } else {
            quant_bits_b4<<<(n + 255) / 256, 256, 0, stream>>>(x, (f32x4*)d_out, n);
        }
    } else {
        float step = (float)(1u << B);
        quant_bits_generic<<<(n + 255) / 256, 256, 0, stream>>>(x, (float*)d_out, n, B, step);
    }
}